// Round 7
// baseline (84.430 us; speedup 1.0000x reference)
//
#include <hip/hip_runtime.h>

// CFNet filter-adaptive convolution (customized FAC), fp32 — fused, 4 px/thread,
// tap-split across wave-groups for 2x occupancy at constant request width.
// feat_in: (8,3,512,512)  kernel: (8,100,256,256)  out: (8,3,256,256)
//
// Index mapping: for output (n,c2,h,w), tap t = 25*tb + 5*j + i:
//   (d,c) = table[tb][c2]
//   feat element = feat[n, c, clamp(2h+(w>>7)+i-2), clamp(4*(w&127)+d+j-2)]
//   kernel tap   = kernel[n, 10*i + 50*(a&1) + (a>>1), h, w],  a = 5*tb+j
//
// Block = 512 threads: waves 0-3 (si=0) compute tb{0,1}, waves 4-7 (si=1)
// compute tb{2,3} for the SAME 256 pixel-quads; partials combined via LDS
// (13-padded rows, conflict-free) + one barrier. Kern taps load as nt float4
// (nt measured +15% in R5/R6 A/B: keeps L2 clean for feat reuse).

#define HH 256
#define WW 256
#define H2 512
#define W2 512
#define KPLANE (HH * WW)   // 65536
#define KP4 (KPLANE / 4)   // 16384 float4 per kernel plane

typedef float f32x4_t __attribute__((ext_vector_type(4)));

// taps for tb = TB0, TB0+1 — all fr/acc indices compile-time (rule #20)
template <int TB0>
__device__ __forceinline__ void taps2(const f32x4_t* __restrict__ kpi,
                                      const float (&fr)[3][20], float (&acc)[3][4]) {
    constexpr int d_tab[4][3] = {{0,1,2},{0,1,3},{0,2,3},{1,2,3}};
    constexpr int c_tab[4][3] = {{0,1,2},{1,2,0},{2,0,1},{0,1,2}};
#pragma unroll
    for (int tt = 0; tt < 2; ++tt) {
        const int tb = TB0 + tt;
#pragma unroll
        for (int j = 0; j < 5; ++j) {
            const int a5 = 5 * tb + j;                    // compile-time
            const int kc = (a5 & 1) * 50 + (a5 >> 1);     // +10*i via kpi
            f32x4_t kv = __builtin_nontemporal_load(kpi + (size_t)kc * KP4);
            const int d0 = d_tab[tb][0], c0 = c_tab[tb][0];
            const int d1 = d_tab[tb][1], c1 = c_tab[tb][1];
            const int d2 = d_tab[tb][2], c2 = c_tab[tb][2];
#pragma unroll
            for (int p = 0; p < 4; ++p) {
                acc[0][p] += kv[p] * fr[c0][d0 + j + 4 * p];
                acc[1][p] += kv[p] * fr[c1][d1 + j + 4 * p];
                acc[2][p] += kv[p] * fr[c2][d2 + j + 4 * p];
            }
        }
    }
}

__global__ __launch_bounds__(512, 4) void fac_fused4s(const float* __restrict__ feat,
                                                      const float* __restrict__ kern,
                                                      float* __restrict__ out) {
    __shared__ float lds[256][13];   // 13-pad: stride 13 % 32 coprime -> conflict-free

    int tid = threadIdx.x;
    int si  = tid >> 8;              // wave-uniform half select (waves 0-3 vs 4-7)
    int lp  = tid & 255;
    int pt  = blockIdx.x * 256 + lp; // pixel-quad thread id, 131072 total
    int qp = pt & 63;                // w = 4*qp
    int h  = (pt >> 6) & 255;
    int n  = pt >> 14;
    int w  = qp << 2;

    int hi = (qp >> 5) & 1;          // = w>>7; row-half select from reshape wrap
    int xb = (qp & 31) << 4;         // = 4*(w&127): 0,16,...,496
    int y2 = 2 * h + hi;

    bool e0 = (qp & 31) == 0;        // left-edge lane class  (xb==0)
    bool e1 = (qp & 31) == 31;       // right-edge lane class (xb==496)
    int wbase = e0 ? 0 : (e1 ? 488 : (xb - 4));   // 24-float window, 16B-aligned

    const f32x4_t* kp4 = (const f32x4_t*)(kern + (size_t)n * 100 * KPLANE +
                                          (size_t)h * WW + w);

    float acc[3][4] = {};

#pragma unroll 1
    for (int i = 0; i < 5; ++i) {
        int sy = min(max(y2 + i - 2, 0), H2 - 1);   // replicate pad in y

        float fr[3][20];
#pragma unroll
        for (int c = 0; c < 3; ++c) {
            const float* rp = feat + ((size_t)(n * 3 + c) * H2 + sy) * W2 + wbase;
            float4 q0 = *(const float4*)(rp);
            float4 q1 = *(const float4*)(rp + 4);
            float4 q2 = *(const float4*)(rp + 8);
            float4 q3 = *(const float4*)(rp + 12);
            float4 q4 = *(const float4*)(rp + 16);
            float4 q5 = *(const float4*)(rp + 20);
            float win[24] = {q0.x, q0.y, q0.z, q0.w, q1.x, q1.y, q1.z, q1.w,
                             q2.x, q2.y, q2.z, q2.w, q3.x, q3.y, q3.z, q3.w,
                             q4.x, q4.y, q4.z, q4.w, q5.x, q5.y, q5.z, q5.w};
#pragma unroll
            for (int o = 0; o < 20; ++o) {
                const int i_in = o + 2;
                const int i_e0 = (o - 2) < 0 ? 0 : (o - 2);
                const int i_e1 = (o + 6) > 23 ? 23 : (o + 6);
                fr[c][o] = e0 ? win[i_e0] : (e1 ? win[i_e1] : win[i_in]);
            }
        }

        const f32x4_t* kpi = kp4 + (size_t)i * 10 * KP4;
        if (si == 0) taps2<0>(kpi, fr, acc);
        else         taps2<2>(kpi, fr, acc);
    }

    if (si == 1) {
#pragma unroll
        for (int c = 0; c < 3; ++c)
#pragma unroll
            for (int p = 0; p < 4; ++p)
                lds[lp][c * 4 + p] = acc[c][p];
    }
    __syncthreads();
    if (si == 0) {
        float* op = out + (size_t)n * 3 * KPLANE + (size_t)h * WW + w;
#pragma unroll
        for (int c = 0; c < 3; ++c) {
            *(float4*)(op + (size_t)c * KPLANE) =
                make_float4(acc[c][0] + lds[lp][c * 4 + 0],
                            acc[c][1] + lds[lp][c * 4 + 1],
                            acc[c][2] + lds[lp][c * 4 + 2],
                            acc[c][3] + lds[lp][c * 4 + 3]);
        }
    }
}

extern "C" void kernel_launch(void* const* d_in, const int* in_sizes, int n_in,
                              void* d_out, int out_size, void* d_ws, size_t ws_size,
                              hipStream_t stream) {
    const float* feat = (const float*)d_in[0];   // 8*3*512*512
    const float* kern = (const float*)d_in[1];   // 8*100*256*256
    float* out = (float*)d_out;                  // 8*3*256*256

    // 512 blocks x 512 threads; each 256-pixel-quad set computed by 2 wave-groups
    fac_fused4s<<<512, 512, 0, stream>>>(feat, kern, out);
}

// Round 8
// 45.059 us; speedup vs baseline: 1.8738x; 1.8738x over previous
//
#include <hip/hip_runtime.h>

// CFNet filter-adaptive convolution (customized FAC), fp32 — fused, 4 px/thread,
// software-pipelined kern stream. R5 geometry (512 blocks x 256 thr, nt float4).
// feat_in: (8,3,512,512)  kernel: (8,100,256,256)  out: (8,3,256,256)
//
// Index mapping: for output (n,c2,h,w), tap t = 25*tb + 5*j + i:
//   (d,c) = table[tb][c2]
//   feat element = feat[n, c, clamp(2h+(w>>7)+i-2), clamp(4*(w&127)+d+j-2)]
//   kernel tap   = kernel[n, 10*i + 50*(a&1) + (a>>1), h, w],  a = 5*tb+j
//
// Pipeline per i-iteration: kvA (tb0,1 of i) was prefetched last iter ->
// compute immediately; kvB (tb2,3 of i) loads at iter start, hidden under
// tb0/1 FMAs; kvN (tb0,1 of i+1) prefetched across the back-edge, hidden
// under tb2/3 FMAs + next iter's feat window loads.

#define HH 256
#define WW 256
#define H2 512
#define W2 512
#define KPLANE (HH * WW)   // 65536
#define KP4 (KPLANE / 4)   // 16384 float4 per kernel plane

typedef float f32x4_t __attribute__((ext_vector_type(4)));

// load the 10 taps of tb{TB0,TB0+1} at kern row-block base kpi
template <int TB0>
__device__ __forceinline__ void load10(const f32x4_t* __restrict__ kpi,
                                       f32x4_t (&kv)[10]) {
#pragma unroll
    for (int tt = 0; tt < 2; ++tt)
#pragma unroll
        for (int j = 0; j < 5; ++j) {
            const int a5 = 5 * (TB0 + tt) + j;            // compile-time
            const int kc = (a5 & 1) * 50 + (a5 >> 1);
            kv[tt * 5 + j] = __builtin_nontemporal_load(kpi + (size_t)kc * KP4);
        }
}

// FMAs for tb{TB0,TB0+1}; all indices compile-time (rule #20 safe)
template <int TB0>
__device__ __forceinline__ void fma10(const f32x4_t (&kv)[10],
                                      const float (&fr)[3][20], float (&acc)[3][4]) {
    constexpr int d_tab[4][3] = {{0,1,2},{0,1,3},{0,2,3},{1,2,3}};
    constexpr int c_tab[4][3] = {{0,1,2},{1,2,0},{2,0,1},{0,1,2}};
#pragma unroll
    for (int tt = 0; tt < 2; ++tt) {
        const int tb = TB0 + tt;
        const int d0 = d_tab[tb][0], c0 = c_tab[tb][0];
        const int d1 = d_tab[tb][1], c1 = c_tab[tb][1];
        const int d2 = d_tab[tb][2], c2 = c_tab[tb][2];
#pragma unroll
        for (int j = 0; j < 5; ++j) {
            f32x4_t kv4 = kv[tt * 5 + j];
#pragma unroll
            for (int p = 0; p < 4; ++p) {
                acc[0][p] += kv4[p] * fr[c0][d0 + j + 4 * p];
                acc[1][p] += kv4[p] * fr[c1][d1 + j + 4 * p];
                acc[2][p] += kv4[p] * fr[c2][d2 + j + 4 * p];
            }
        }
    }
}

__global__ __launch_bounds__(256, 2) void fac_fused4p(const float* __restrict__ feat,
                                                      const float* __restrict__ kern,
                                                      float* __restrict__ out) {
    int t  = blockIdx.x * 256 + threadIdx.x;   // 131072 threads total
    int qp = t & 63;             // pixel-quad index: w = 4*qp
    int h  = (t >> 6) & 255;
    int n  = t >> 14;
    int w  = qp << 2;

    int hi = (qp >> 5) & 1;      // = w>>7; row-half select from reshape wrap
    int xb = (qp & 31) << 4;     // = 4*(w&127): 0,16,...,496
    int y2 = 2 * h + hi;

    bool e0 = (qp & 31) == 0;    // left-edge lane class  (xb==0)
    bool e1 = (qp & 31) == 31;   // right-edge lane class (xb==496)
    int wbase = e0 ? 0 : (e1 ? 488 : (xb - 4));   // 24-float window, 16B-aligned

    const f32x4_t* kp4 = (const f32x4_t*)(kern + (size_t)n * 100 * KPLANE +
                                          (size_t)h * WW + w);

    float acc[3][4] = {};
    f32x4_t kvA[10], kvB[10], kvN[10] = {};

    load10<0>(kp4, kvA);         // prologue: tb0,1 taps of i=0

#pragma unroll 1
    for (int i = 0; i < 5; ++i) {
        int sy = min(max(y2 + i - 2, 0), H2 - 1);   // replicate pad in y

        // 24-float window per channel; 20 taps extracted w/ compile-time idx
        float fr[3][20];
#pragma unroll
        for (int c = 0; c < 3; ++c) {
            const float* rp = feat + ((size_t)(n * 3 + c) * H2 + sy) * W2 + wbase;
            float4 q0 = *(const float4*)(rp);
            float4 q1 = *(const float4*)(rp + 4);
            float4 q2 = *(const float4*)(rp + 8);
            float4 q3 = *(const float4*)(rp + 12);
            float4 q4 = *(const float4*)(rp + 16);
            float4 q5 = *(const float4*)(rp + 20);
            float win[24] = {q0.x, q0.y, q0.z, q0.w, q1.x, q1.y, q1.z, q1.w,
                             q2.x, q2.y, q2.z, q2.w, q3.x, q3.y, q3.z, q3.w,
                             q4.x, q4.y, q4.z, q4.w, q5.x, q5.y, q5.z, q5.w};
#pragma unroll
            for (int o = 0; o < 20; ++o) {
                const int i_in = o + 2;
                const int i_e0 = (o - 2) < 0 ? 0 : (o - 2);
                const int i_e1 = (o + 6) > 23 ? 23 : (o + 6);
                fr[c][o] = e0 ? win[i_e0] : (e1 ? win[i_e1] : win[i_in]);
            }
        }

        const f32x4_t* kpi = kp4 + (size_t)i * 10 * KP4;
        load10<2>(kpi, kvB);                 // tb2,3 of current i
        if (i < 4) load10<0>(kpi + 10 * KP4, kvN);   // tb0,1 of i+1 (back-edge prefetch)

        fma10<0>(kvA, fr, acc);              // data ready (prefetched last iter)
        fma10<2>(kvB, fr, acc);              // hidden under fma10<0>

#pragma unroll
        for (int u = 0; u < 10; ++u) kvA[u] = kvN[u];
    }

    float* op = out + (size_t)n * 3 * KPLANE + (size_t)h * WW + w;
#pragma unroll
    for (int c = 0; c < 3; ++c) {
        *(float4*)(op + (size_t)c * KPLANE) =
            make_float4(acc[c][0], acc[c][1], acc[c][2], acc[c][3]);
    }
}

extern "C" void kernel_launch(void* const* d_in, const int* in_sizes, int n_in,
                              void* d_out, int out_size, void* d_ws, size_t ws_size,
                              hipStream_t stream) {
    const float* feat = (const float*)d_in[0];   // 8*3*512*512
    const float* kern = (const float*)d_in[1];   // 8*100*256*256
    float* out = (float*)d_out;                  // 8*3*256*256

    // 131072 threads, 4 pixels each; 512 blocks
    fac_fused4p<<<512, 256, 0, stream>>>(feat, kern, out);
}

// Round 9
// 43.630 us; speedup vs baseline: 1.9351x; 1.0328x over previous
//
#include <hip/hip_runtime.h>

// CFNet filter-adaptive convolution (customized FAC), fp32 — fused, 4 px/thread,
// software-pipelined kern stream + XCD-chunked block swizzle (T1).
// feat_in: (8,3,512,512)  kernel: (8,100,256,256)  out: (8,3,256,256)
//
// Index mapping: for output (n,c2,h,w), tap t = 25*tb + 5*j + i:
//   (d,c) = table[tb][c2]
//   feat element = feat[n, c, clamp(2h+(w>>7)+i-2), clamp(4*(w&127)+d+j-2)]
//   kernel tap   = kernel[n, 10*i + 50*(a&1) + (a>>1), h, w],  a = 5*tb+j
//
// Swizzle: adjacent logical blocks share ~40% of their feat rows; chunked
// XCD mapping (512 blocks = 8 chunks x 64) keeps sharers on one XCD's L2,
// removing duplicated feat HBM fills. Kern has zero inter-block reuse.

#define HH 256
#define WW 256
#define H2 512
#define W2 512
#define KPLANE (HH * WW)   // 65536
#define KP4 (KPLANE / 4)   // 16384 float4 per kernel plane

typedef float f32x4_t __attribute__((ext_vector_type(4)));

template <int TB0>
__device__ __forceinline__ void load10(const f32x4_t* __restrict__ kpi,
                                       f32x4_t (&kv)[10]) {
#pragma unroll
    for (int tt = 0; tt < 2; ++tt)
#pragma unroll
        for (int j = 0; j < 5; ++j) {
            const int a5 = 5 * (TB0 + tt) + j;            // compile-time
            const int kc = (a5 & 1) * 50 + (a5 >> 1);
            kv[tt * 5 + j] = __builtin_nontemporal_load(kpi + (size_t)kc * KP4);
        }
}

template <int TB0>
__device__ __forceinline__ void fma10(const f32x4_t (&kv)[10],
                                      const float (&fr)[3][20], float (&acc)[3][4]) {
    constexpr int d_tab[4][3] = {{0,1,2},{0,1,3},{0,2,3},{1,2,3}};
    constexpr int c_tab[4][3] = {{0,1,2},{1,2,0},{2,0,1},{0,1,2}};
#pragma unroll
    for (int tt = 0; tt < 2; ++tt) {
        const int tb = TB0 + tt;
        const int d0 = d_tab[tb][0], c0 = c_tab[tb][0];
        const int d1 = d_tab[tb][1], c1 = c_tab[tb][1];
        const int d2 = d_tab[tb][2], c2 = c_tab[tb][2];
#pragma unroll
        for (int j = 0; j < 5; ++j) {
            f32x4_t kv4 = kv[tt * 5 + j];
#pragma unroll
            for (int p = 0; p < 4; ++p) {
                acc[0][p] += kv4[p] * fr[c0][d0 + j + 4 * p];
                acc[1][p] += kv4[p] * fr[c1][d1 + j + 4 * p];
                acc[2][p] += kv4[p] * fr[c2][d2 + j + 4 * p];
            }
        }
    }
}

__global__ __launch_bounds__(256, 2) void fac_fused4p(const float* __restrict__ feat,
                                                      const float* __restrict__ kern,
                                                      float* __restrict__ out) {
    // XCD-chunked swizzle: 512 blocks -> 8 XCD chunks of 64 contiguous blocks
    int bid = ((int)blockIdx.x & 7) * 64 + ((int)blockIdx.x >> 3);
    int t  = bid * 256 + threadIdx.x;   // 131072 threads total
    int qp = t & 63;             // pixel-quad index: w = 4*qp
    int h  = (t >> 6) & 255;
    int n  = t >> 14;
    int w  = qp << 2;

    int hi = (qp >> 5) & 1;      // = w>>7; row-half select from reshape wrap
    int xb = (qp & 31) << 4;     // = 4*(w&127): 0,16,...,496
    int y2 = 2 * h + hi;

    bool e0 = (qp & 31) == 0;    // left-edge lane class  (xb==0)
    bool e1 = (qp & 31) == 31;   // right-edge lane class (xb==496)
    int wbase = e0 ? 0 : (e1 ? 488 : (xb - 4));   // 24-float window, 16B-aligned

    const f32x4_t* kp4 = (const f32x4_t*)(kern + (size_t)n * 100 * KPLANE +
                                          (size_t)h * WW + w);

    float acc[3][4] = {};
    f32x4_t kvA[10], kvB[10], kvN[10] = {};

    load10<0>(kp4, kvA);         // prologue: tb0,1 taps of i=0

#pragma unroll 1
    for (int i = 0; i < 5; ++i) {
        int sy = min(max(y2 + i - 2, 0), H2 - 1);   // replicate pad in y

        float fr[3][20];
#pragma unroll
        for (int c = 0; c < 3; ++c) {
            const float* rp = feat + ((size_t)(n * 3 + c) * H2 + sy) * W2 + wbase;
            float4 q0 = *(const float4*)(rp);
            float4 q1 = *(const float4*)(rp + 4);
            float4 q2 = *(const float4*)(rp + 8);
            float4 q3 = *(const float4*)(rp + 12);
            float4 q4 = *(const float4*)(rp + 16);
            float4 q5 = *(const float4*)(rp + 20);
            float win[24] = {q0.x, q0.y, q0.z, q0.w, q1.x, q1.y, q1.z, q1.w,
                             q2.x, q2.y, q2.z, q2.w, q3.x, q3.y, q3.z, q3.w,
                             q4.x, q4.y, q4.z, q4.w, q5.x, q5.y, q5.z, q5.w};
#pragma unroll
            for (int o = 0; o < 20; ++o) {
                const int i_in = o + 2;
                const int i_e0 = (o - 2) < 0 ? 0 : (o - 2);
                const int i_e1 = (o + 6) > 23 ? 23 : (o + 6);
                fr[c][o] = e0 ? win[i_e0] : (e1 ? win[i_e1] : win[i_in]);
            }
        }

        const f32x4_t* kpi = kp4 + (size_t)i * 10 * KP4;
        load10<2>(kpi, kvB);                 // tb2,3 of current i
        if (i < 4) load10<0>(kpi + 10 * KP4, kvN);   // tb0,1 of i+1

        fma10<0>(kvA, fr, acc);
        fma10<2>(kvB, fr, acc);

#pragma unroll
        for (int u = 0; u < 10; ++u) kvA[u] = kvN[u];
    }

    float* op = out + (size_t)n * 3 * KPLANE + (size_t)h * WW + w;
#pragma unroll
    for (int c = 0; c < 3; ++c) {
        *(float4*)(op + (size_t)c * KPLANE) =
            make_float4(acc[c][0], acc[c][1], acc[c][2], acc[c][3]);
    }
}

extern "C" void kernel_launch(void* const* d_in, const int* in_sizes, int n_in,
                              void* d_out, int out_size, void* d_ws, size_t ws_size,
                              hipStream_t stream) {
    const float* feat = (const float*)d_in[0];   // 8*3*512*512
    const float* kern = (const float*)d_in[1];   // 8*100*256*256
    float* out = (float*)d_out;                  // 8*3*256*256

    fac_fused4p<<<512, 256, 0, stream>>>(feat, kern, out);
}